// Round 3
// baseline (876.774 us; speedup 1.0000x reference)
//
#include <hip/hip_runtime.h>

#define N_NODES 100000
#define N_EDGES 1280000
#define N_GRAPHS 512
#define SCAN_BLOCKS 391   // ceil(100000/256)

// ---------------- degree / norm ----------------

__global__ void count_deg(const int* __restrict__ dst, int* __restrict__ cnt) {
    int e = blockIdx.x * blockDim.x + threadIdx.x;
    if (e < N_EDGES) atomicAdd(&cnt[dst[e]], 1);
}

__global__ void compute_dinv(const int* __restrict__ cnt, float* __restrict__ dinv) {
    int i = blockIdx.x * blockDim.x + threadIdx.x;
    if (i < N_NODES) dinv[i] = 1.0f / sqrtf((float)cnt[i] + 1.0f);
}

// ---------------- exclusive prefix scan (3-kernel) ----------------

__global__ void scan1(const int* __restrict__ cnt, int* __restrict__ offs, int* __restrict__ bsum) {
    __shared__ int s[256];
    int t = threadIdx.x;
    int i = blockIdx.x * 256 + t;
    int v = (i < N_NODES) ? cnt[i] : 0;
    s[t] = v; __syncthreads();
    for (int d = 1; d < 256; d <<= 1) {
        int x = (t >= d) ? s[t - d] : 0;
        __syncthreads();
        s[t] += x;
        __syncthreads();
    }
    if (i < N_NODES) offs[i] = s[t] - v;
    if (t == 255) bsum[blockIdx.x] = s[t];
}

__global__ void scan2(int* __restrict__ bsum, int nb) {
    __shared__ int s[512];
    int t = threadIdx.x;
    int v = (t < nb) ? bsum[t] : 0;
    s[t] = v; __syncthreads();
    for (int d = 1; d < 512; d <<= 1) {
        int x = (t >= d) ? s[t - d] : 0;
        __syncthreads();
        s[t] += x;
        __syncthreads();
    }
    if (t < nb) bsum[t] = s[t] - v;
}

__global__ void scan3(int* __restrict__ offs, const int* __restrict__ bsum) {
    int i = blockIdx.x * 256 + threadIdx.x;
    if (i < N_NODES) offs[i] += bsum[blockIdx.x];
    if (i == 0) offs[N_NODES] = N_EDGES;
}

// ---------------- CSR fill ----------------

__global__ void fill_csr(const int* __restrict__ src, const int* __restrict__ dst,
                         const int* __restrict__ offs, int* __restrict__ cursor,
                         const float* __restrict__ dinv,
                         int* __restrict__ csr_src, float* __restrict__ csr_norm) {
    int e = blockIdx.x * blockDim.x + threadIdx.x;
    if (e < N_EDGES) {
        int d = dst[e], s = src[e];
        int p = offs[d] + atomicAdd(&cursor[d], 1);
        csr_src[p] = s;
        csr_norm[p] = dinv[s] * dinv[d];
    }
}

// ---------------- fp32 GEMM [N x 64] @ [64 x 64], 128-row tiles ----------------

__global__ __launch_bounds__(256) void gemm64(const float* __restrict__ X,
                                              const float* __restrict__ W,
                                              float* __restrict__ H) {
    __shared__ float Xt[64][132];   // transposed: Xt[k][node], stride 132 (528B, 16B-aligned)
    __shared__ float Ws[64][64];    // Ws[k][j]
    int t = threadIdx.x;
    int base = blockIdx.x * 128;

    {   // load W (4096 floats) with float4
        const float4* Wv = (const float4*)W;
        float4* Wsv = (float4*)Ws;
        #pragma unroll
        for (int q = 0; q < 4; q++) Wsv[t + q * 256] = Wv[t + q * 256];
    }
    {   // load X tile (128 rows), transpose into Xt
        int r = t >> 1;
        int k0 = (t & 1) * 32;
        int row = base + r;
        if (row < N_NODES) {
            const float4* xr = (const float4*)(X + (size_t)row * 64 + k0);
            #pragma unroll
            for (int q = 0; q < 8; q++) {
                float4 v = xr[q];
                int k = k0 + q * 4;
                Xt[k + 0][r] = v.x; Xt[k + 1][r] = v.y;
                Xt[k + 2][r] = v.z; Xt[k + 3][r] = v.w;
            }
        } else {
            #pragma unroll
            for (int q = 0; q < 32; q++) Xt[k0 + q][r] = 0.f;
        }
    }
    __syncthreads();

    int j0 = (t & 15) * 4;        // 4 output cols
    int n0 = (t >> 4) * 8;        // 8 output rows
    float acc[8][4] = {};
    #pragma unroll
    for (int k = 0; k < 64; k++) {
        float4 w = *(const float4*)&Ws[k][j0];
        float4 a = *(const float4*)&Xt[k][n0];
        float4 b = *(const float4*)&Xt[k][n0 + 4];
        acc[0][0] += a.x * w.x; acc[0][1] += a.x * w.y; acc[0][2] += a.x * w.z; acc[0][3] += a.x * w.w;
        acc[1][0] += a.y * w.x; acc[1][1] += a.y * w.y; acc[1][2] += a.y * w.z; acc[1][3] += a.y * w.w;
        acc[2][0] += a.z * w.x; acc[2][1] += a.z * w.y; acc[2][2] += a.z * w.z; acc[2][3] += a.z * w.w;
        acc[3][0] += a.w * w.x; acc[3][1] += a.w * w.y; acc[3][2] += a.w * w.z; acc[3][3] += a.w * w.w;
        acc[4][0] += b.x * w.x; acc[4][1] += b.x * w.y; acc[4][2] += b.x * w.z; acc[4][3] += b.x * w.w;
        acc[5][0] += b.y * w.x; acc[5][1] += b.y * w.y; acc[5][2] += b.y * w.z; acc[5][3] += b.y * w.w;
        acc[6][0] += b.z * w.x; acc[6][1] += b.z * w.y; acc[6][2] += b.z * w.z; acc[6][3] += b.z * w.w;
        acc[7][0] += b.w * w.x; acc[7][1] += b.w * w.y; acc[7][2] += b.w * w.z; acc[7][3] += b.w * w.w;
    }
    #pragma unroll
    for (int i = 0; i < 8; i++) {
        int row = base + n0 + i;
        if (row < N_NODES) {
            float4 o; o.x = acc[i][0]; o.y = acc[i][1]; o.z = acc[i][2]; o.w = acc[i][3];
            *(float4*)(H + (size_t)row * 64 + j0) = o;
        }
    }
}

// ------------- aggregation: wave per node, 4 edge-subgroups x 16 feature-quads -------------
// lane = eg*16 + fq ; each lane does float4 gathers; 8 edges in flight via unroll x2.

__device__ inline void agg_body(const float4* __restrict__ H4, int wid, int lane,
                                const int* __restrict__ offs,
                                const int* __restrict__ csr_src,
                                const float* __restrict__ csr_norm,
                                const float* __restrict__ dinv,
                                float4& out) {
    int eg = lane >> 4;       // 0..3
    int fq = lane & 15;       // feature quad
    int beg = offs[wid], end = offs[wid + 1];
    float di = dinv[wid];
    float4 self = H4[(size_t)wid * 16 + fq];

    float4 a0 = {0.f, 0.f, 0.f, 0.f};
    float4 a1 = {0.f, 0.f, 0.f, 0.f};
    int e = beg + eg;
    for (; e + 4 < end; e += 8) {
        int   s0 = csr_src[e];      int   s1 = csr_src[e + 4];
        float n0 = csr_norm[e];     float n1 = csr_norm[e + 4];
        float4 h0 = H4[(size_t)s0 * 16 + fq];
        float4 h1 = H4[(size_t)s1 * 16 + fq];
        a0.x += h0.x * n0; a0.y += h0.y * n0; a0.z += h0.z * n0; a0.w += h0.w * n0;
        a1.x += h1.x * n1; a1.y += h1.y * n1; a1.z += h1.z * n1; a1.w += h1.w * n1;
    }
    if (e < end) {
        int s0 = csr_src[e]; float n0 = csr_norm[e];
        float4 h0 = H4[(size_t)s0 * 16 + fq];
        a0.x += h0.x * n0; a0.y += h0.y * n0; a0.z += h0.z * n0; a0.w += h0.w * n0;
    }
    a0.x += a1.x; a0.y += a1.y; a0.z += a1.z; a0.w += a1.w;
    // reduce across the 4 edge-subgroups
    a0.x += __shfl_xor(a0.x, 16); a0.y += __shfl_xor(a0.y, 16);
    a0.z += __shfl_xor(a0.z, 16); a0.w += __shfl_xor(a0.w, 16);
    a0.x += __shfl_xor(a0.x, 32); a0.y += __shfl_xor(a0.y, 32);
    a0.z += __shfl_xor(a0.z, 32); a0.w += __shfl_xor(a0.w, 32);
    float dd = di * di;
    out.x = a0.x + self.x * dd; out.y = a0.y + self.y * dd;
    out.z = a0.z + self.z * dd; out.w = a0.w + self.w * dd;
}

__global__ __launch_bounds__(256) void agg_gcn(const float* __restrict__ H,
                                               const int* __restrict__ offs,
                                               const int* __restrict__ csr_src,
                                               const float* __restrict__ csr_norm,
                                               const float* __restrict__ dinv,
                                               const float* __restrict__ bias,
                                               float* __restrict__ Out) {
    int wid = (blockIdx.x * 256 + threadIdx.x) >> 6;
    int lane = threadIdx.x & 63;
    if (wid >= N_NODES) return;
    float4 r;
    agg_body((const float4*)H, wid, lane, offs, csr_src, csr_norm, dinv, r);
    int fq = lane & 15;
    if ((lane >> 4) == 0) {
        float4 b4 = ((const float4*)bias)[fq];
        float4 o;
        o.x = fmaxf(r.x + b4.x, 0.f); o.y = fmaxf(r.y + b4.y, 0.f);
        o.z = fmaxf(r.z + b4.z, 0.f); o.w = fmaxf(r.w + b4.w, 0.f);
        ((float4*)Out)[(size_t)wid * 16 + fq] = o;
    }
}

__global__ __launch_bounds__(256) void agg_gcn_pool(const float* __restrict__ H,
                                                    const int* __restrict__ offs,
                                                    const int* __restrict__ csr_src,
                                                    const float* __restrict__ csr_norm,
                                                    const float* __restrict__ dinv,
                                                    const float* __restrict__ bias,
                                                    const float* __restrict__ fcw,
                                                    float* __restrict__ p) {
    int wid = (blockIdx.x * 256 + threadIdx.x) >> 6;
    int lane = threadIdx.x & 63;
    if (wid >= N_NODES) return;
    float4 r;
    agg_body((const float4*)H, wid, lane, offs, csr_src, csr_norm, dinv, r);
    int fq = lane & 15;
    float4 b4 = ((const float4*)bias)[fq];
    float4 f4 = ((const float4*)fcw)[fq];
    float v = fmaxf(r.x + b4.x, 0.f) * f4.x + fmaxf(r.y + b4.y, 0.f) * f4.y
            + fmaxf(r.z + b4.z, 0.f) * f4.z + fmaxf(r.w + b4.w, 0.f) * f4.w;
    // sum across the 16 feature-quads (all 4 subgroups already identical)
    v += __shfl_xor(v, 1); v += __shfl_xor(v, 2);
    v += __shfl_xor(v, 4); v += __shfl_xor(v, 8);
    if (lane == 0) p[wid] = v;
}

// ---------------- per-graph segmented mean via binary search (no atomics) ----

__device__ inline int lower_bound_batch(const int* __restrict__ batch, int key) {
    int lo = 0, hi = N_NODES;
    while (lo < hi) {
        int mid = (lo + hi) >> 1;
        if (batch[mid] < key) lo = mid + 1; else hi = mid;
    }
    return lo;
}

__global__ __launch_bounds__(256) void graph_reduce(const float* __restrict__ p,
                                                    const int* __restrict__ batch,
                                                    const float* __restrict__ fcb,
                                                    float* __restrict__ out) {
    __shared__ float red[4];
    int g = blockIdx.x;
    int s0 = lower_bound_batch(batch, g);
    int s1 = lower_bound_batch(batch, g + 1);
    float acc = 0.f;
    for (int i = s0 + threadIdx.x; i < s1; i += 256) acc += p[i];
    #pragma unroll
    for (int o = 32; o > 0; o >>= 1) acc += __shfl_xor(acc, o);
    int lane = threadIdx.x & 63, wv = threadIdx.x >> 6;
    if (lane == 0) red[wv] = acc;
    __syncthreads();
    if (threadIdx.x == 0) {
        float sum = red[0] + red[1] + red[2] + red[3];
        out[g] = sum / fmaxf((float)(s1 - s0), 1.f) + fcb[0];
    }
}

// ---------------- launch ----------------

extern "C" void kernel_launch(void* const* d_in, const int* in_sizes, int n_in,
                              void* d_out, int out_size, void* d_ws, size_t ws_size,
                              hipStream_t stream) {
    const float* x    = (const float*)d_in[0];
    const int*   ei   = (const int*)d_in[1];
    const int*   batch= (const int*)d_in[2];
    const float* w0   = (const float*)d_in[3];
    const float* b0   = (const float*)d_in[4];
    const float* w1   = (const float*)d_in[5];
    const float* b1   = (const float*)d_in[6];
    const float* w2   = (const float*)d_in[7];
    const float* b2   = (const float*)d_in[8];
    const float* fcw  = (const float*)d_in[9];
    const float* fcb  = (const float*)d_in[10];
    float* out = (float*)d_out;

    const int* src_e = ei;              // edge_index[0]
    const int* dst_e = ei + N_EDGES;    // edge_index[1]

    char* w = (char*)d_ws;
    size_t o = 0;
    int*   deg_cnt  = (int*)(w + o);   o += (size_t)N_NODES * 4;
    float* dinv     = (float*)(w + o); o += (size_t)N_NODES * 4;
    int*   offs     = (int*)(w + o);   o += (size_t)N_NODES * 4;   // +1 slot folded below
    int*   cursor   = (int*)(w + o);   o += (size_t)(N_NODES + 8) * 4;
    int*   bsum     = (int*)(w + o);   o += 512 * 4;
    int*   csr_src  = (int*)(w + o);   o += (size_t)N_EDGES * 4;
    float* csr_norm = (float*)(w + o); o += (size_t)N_EDGES * 4;
    float* bufA     = (float*)(w + o); o += (size_t)N_NODES * 64 * 4;
    float* bufB     = (float*)(w + o); o += (size_t)N_NODES * 64 * 4;
    float* pvec     = (float*)(w + o); o += (size_t)N_NODES * 4;
    // NOTE: offs needs N_NODES+1 ints; it borrows the first slot of cursor's padding:
    // layout places cursor right after offs with 8 ints of slack, so offs[N_NODES]
    // overlaps cursor[-?] -- to keep it safe, offs region above actually extends into
    // the (N_NODES+8) cursor block's first int. We shift cursor by 1:
    cursor = (int*)((char*)cursor + 16);   // keep 16B alignment, offs[N_NODES..] free

    hipMemsetAsync(deg_cnt, 0, (size_t)N_NODES * 4, stream);
    hipMemsetAsync(cursor,  0, (size_t)N_NODES * 4, stream);

    count_deg<<<(N_EDGES + 255) / 256, 256, 0, stream>>>(dst_e, deg_cnt);
    compute_dinv<<<(N_NODES + 255) / 256, 256, 0, stream>>>(deg_cnt, dinv);
    scan1<<<SCAN_BLOCKS, 256, 0, stream>>>(deg_cnt, offs, bsum);
    scan2<<<1, 512, 0, stream>>>(bsum, SCAN_BLOCKS);
    scan3<<<SCAN_BLOCKS, 256, 0, stream>>>(offs, bsum);
    fill_csr<<<(N_EDGES + 255) / 256, 256, 0, stream>>>(src_e, dst_e, offs, cursor, dinv,
                                                        csr_src, csr_norm);

    const int GEMM_BLOCKS = (N_NODES + 127) / 128;  // 782
    const int AGG_BLOCKS  = (N_NODES + 3) / 4;      // 25000

    gemm64<<<GEMM_BLOCKS, 256, 0, stream>>>(x, w0, bufA);
    agg_gcn<<<AGG_BLOCKS, 256, 0, stream>>>(bufA, offs, csr_src, csr_norm, dinv, b0, bufB);

    gemm64<<<GEMM_BLOCKS, 256, 0, stream>>>(bufB, w1, bufA);
    agg_gcn<<<AGG_BLOCKS, 256, 0, stream>>>(bufA, offs, csr_src, csr_norm, dinv, b1, bufB);

    gemm64<<<GEMM_BLOCKS, 256, 0, stream>>>(bufB, w2, bufA);
    agg_gcn_pool<<<AGG_BLOCKS, 256, 0, stream>>>(bufA, offs, csr_src, csr_norm, dinv, b2,
                                                 fcw, pvec);

    graph_reduce<<<N_GRAPHS, 256, 0, stream>>>(pvec, batch, fcb, out);
}

// Round 4
// 557.693 us; speedup vs baseline: 1.5721x; 1.5721x over previous
//
#include <hip/hip_runtime.h>

#define N_NODES 100000
#define N_EDGES 1280000
#define N_GRAPHS 512
#define SCAN_BLOCKS 391   // ceil(100000/256)

// ---------------- degree / norm ----------------

__global__ void count_deg(const int* __restrict__ dst, int* __restrict__ cnt) {
    int e = blockIdx.x * blockDim.x + threadIdx.x;
    if (e < N_EDGES) atomicAdd(&cnt[dst[e]], 1);
}

__global__ void compute_dinv(const int* __restrict__ cnt, float* __restrict__ dinv) {
    int i = blockIdx.x * blockDim.x + threadIdx.x;
    if (i < N_NODES) dinv[i] = 1.0f / sqrtf((float)cnt[i] + 1.0f);
}

// ---------------- exclusive prefix scan (3-kernel) ----------------

__global__ void scan1(const int* __restrict__ cnt, int* __restrict__ offs, int* __restrict__ bsum) {
    __shared__ int s[256];
    int t = threadIdx.x;
    int i = blockIdx.x * 256 + t;
    int v = (i < N_NODES) ? cnt[i] : 0;
    s[t] = v; __syncthreads();
    for (int d = 1; d < 256; d <<= 1) {
        int x = (t >= d) ? s[t - d] : 0;
        __syncthreads();
        s[t] += x;
        __syncthreads();
    }
    if (i < N_NODES) offs[i] = s[t] - v;
    if (t == 255) bsum[blockIdx.x] = s[t];
}

__global__ void scan2(int* __restrict__ bsum, int nb) {
    __shared__ int s[512];
    int t = threadIdx.x;
    int v = (t < nb) ? bsum[t] : 0;
    s[t] = v; __syncthreads();
    for (int d = 1; d < 512; d <<= 1) {
        int x = (t >= d) ? s[t - d] : 0;
        __syncthreads();
        s[t] += x;
        __syncthreads();
    }
    if (t < nb) bsum[t] = s[t] - v;
}

__global__ void scan3(int* __restrict__ offs, const int* __restrict__ bsum) {
    int i = blockIdx.x * 256 + threadIdx.x;
    if (i < N_NODES) offs[i] += bsum[blockIdx.x];
    if (i == 0) offs[N_NODES] = N_EDGES;
}

// ---------------- CSR fill ----------------

__global__ void fill_csr(const int* __restrict__ src, const int* __restrict__ dst,
                         const int* __restrict__ offs, int* __restrict__ cursor,
                         const float* __restrict__ dinv,
                         int* __restrict__ csr_src, float* __restrict__ csr_norm) {
    int e = blockIdx.x * blockDim.x + threadIdx.x;
    if (e < N_EDGES) {
        int d = dst[e], s = src[e];
        int p = offs[d] + atomicAdd(&cursor[d], 1);
        csr_src[p] = s;
        csr_norm[p] = dinv[s] * dinv[d];
    }
}

// ---------------- fp32 GEMM [N x 64] @ [64 x 64], 64-row tiles ----------------
// R1-proven version: acc[4][4] (16 VGPRs), no spills. DO NOT grow the
// accumulator tile: R2's acc[8][4]+128-row variant hit VGPR=256 -> scratch
// spills -> 217MB of spill writes per dispatch, 165us/gemm.

__global__ __launch_bounds__(256) void gemm64(const float* __restrict__ X,
                                              const float* __restrict__ W,
                                              float* __restrict__ H) {
    __shared__ float Xt[64][68];   // transposed tile: Xt[k][node]
    __shared__ float Ws[64][64];   // Ws[k][j]
    int t = threadIdx.x;
    int base = blockIdx.x * 64;

    {
        const float4* Wv = (const float4*)W;
        float4* Wsv = (float4*)Ws;
        Wsv[t]        = Wv[t];
        Wsv[t + 256]  = Wv[t + 256];
        Wsv[t + 512]  = Wv[t + 512];
        Wsv[t + 768]  = Wv[t + 768];
    }
    {
        int r = t >> 2;
        int k0 = (t & 3) * 16;
        int row = base + r;
        if (row < N_NODES) {
            const float4* xr = (const float4*)(X + (size_t)row * 64 + k0);
            #pragma unroll
            for (int q = 0; q < 4; q++) {
                float4 v = xr[q];
                int k = k0 + q * 4;
                Xt[k + 0][r] = v.x; Xt[k + 1][r] = v.y;
                Xt[k + 2][r] = v.z; Xt[k + 3][r] = v.w;
            }
        } else {
            #pragma unroll
            for (int q = 0; q < 4; q++) {
                int k = k0 + q * 4;
                Xt[k][r] = 0.f; Xt[k + 1][r] = 0.f; Xt[k + 2][r] = 0.f; Xt[k + 3][r] = 0.f;
            }
        }
    }
    __syncthreads();

    int tx = t & 15, ty = t >> 4;
    int j0 = tx * 4, n0 = ty * 4;
    float acc[4][4] = {};
    #pragma unroll
    for (int k = 0; k < 64; k++) {
        float4 a = *(const float4*)&Xt[k][n0];
        float4 w = *(const float4*)&Ws[k][j0];
        acc[0][0] += a.x * w.x; acc[0][1] += a.x * w.y; acc[0][2] += a.x * w.z; acc[0][3] += a.x * w.w;
        acc[1][0] += a.y * w.x; acc[1][1] += a.y * w.y; acc[1][2] += a.y * w.z; acc[1][3] += a.y * w.w;
        acc[2][0] += a.z * w.x; acc[2][1] += a.z * w.y; acc[2][2] += a.z * w.z; acc[2][3] += a.z * w.w;
        acc[3][0] += a.w * w.x; acc[3][1] += a.w * w.y; acc[3][2] += a.w * w.z; acc[3][3] += a.w * w.w;
    }
    #pragma unroll
    for (int i = 0; i < 4; i++) {
        int row = base + n0 + i;
        if (row < N_NODES) {
            float4 o; o.x = acc[i][0]; o.y = acc[i][1]; o.z = acc[i][2]; o.w = acc[i][3];
            *(float4*)(H + (size_t)row * 64 + j0) = o;
        }
    }
}

// ------------- aggregation: wave per node, 4 edge-subgroups x 16 feature-quads -------------
// lane = eg*16 + fq ; each lane does float4 gathers; 8 edges in flight via unroll x2.

__device__ inline void agg_body(const float4* __restrict__ H4, int wid, int lane,
                                const int* __restrict__ offs,
                                const int* __restrict__ csr_src,
                                const float* __restrict__ csr_norm,
                                const float* __restrict__ dinv,
                                float4& out) {
    int eg = lane >> 4;       // 0..3
    int fq = lane & 15;       // feature quad
    int beg = offs[wid], end = offs[wid + 1];
    float di = dinv[wid];
    float4 self = H4[(size_t)wid * 16 + fq];

    float4 a0 = {0.f, 0.f, 0.f, 0.f};
    float4 a1 = {0.f, 0.f, 0.f, 0.f};
    int e = beg + eg;
    for (; e + 4 < end; e += 8) {
        int   s0 = csr_src[e];      int   s1 = csr_src[e + 4];
        float n0 = csr_norm[e];     float n1 = csr_norm[e + 4];
        float4 h0 = H4[(size_t)s0 * 16 + fq];
        float4 h1 = H4[(size_t)s1 * 16 + fq];
        a0.x += h0.x * n0; a0.y += h0.y * n0; a0.z += h0.z * n0; a0.w += h0.w * n0;
        a1.x += h1.x * n1; a1.y += h1.y * n1; a1.z += h1.z * n1; a1.w += h1.w * n1;
    }
    if (e < end) {
        int s0 = csr_src[e]; float n0 = csr_norm[e];
        float4 h0 = H4[(size_t)s0 * 16 + fq];
        a0.x += h0.x * n0; a0.y += h0.y * n0; a0.z += h0.z * n0; a0.w += h0.w * n0;
    }
    a0.x += a1.x; a0.y += a1.y; a0.z += a1.z; a0.w += a1.w;
    // reduce across the 4 edge-subgroups
    a0.x += __shfl_xor(a0.x, 16); a0.y += __shfl_xor(a0.y, 16);
    a0.z += __shfl_xor(a0.z, 16); a0.w += __shfl_xor(a0.w, 16);
    a0.x += __shfl_xor(a0.x, 32); a0.y += __shfl_xor(a0.y, 32);
    a0.z += __shfl_xor(a0.z, 32); a0.w += __shfl_xor(a0.w, 32);
    float dd = di * di;
    out.x = a0.x + self.x * dd; out.y = a0.y + self.y * dd;
    out.z = a0.z + self.z * dd; out.w = a0.w + self.w * dd;
}

__global__ __launch_bounds__(256) void agg_gcn(const float* __restrict__ H,
                                               const int* __restrict__ offs,
                                               const int* __restrict__ csr_src,
                                               const float* __restrict__ csr_norm,
                                               const float* __restrict__ dinv,
                                               const float* __restrict__ bias,
                                               float* __restrict__ Out) {
    int wid = (blockIdx.x * 256 + threadIdx.x) >> 6;
    int lane = threadIdx.x & 63;
    if (wid >= N_NODES) return;
    float4 r;
    agg_body((const float4*)H, wid, lane, offs, csr_src, csr_norm, dinv, r);
    int fq = lane & 15;
    if ((lane >> 4) == 0) {
        float4 b4 = ((const float4*)bias)[fq];
        float4 o;
        o.x = fmaxf(r.x + b4.x, 0.f); o.y = fmaxf(r.y + b4.y, 0.f);
        o.z = fmaxf(r.z + b4.z, 0.f); o.w = fmaxf(r.w + b4.w, 0.f);
        ((float4*)Out)[(size_t)wid * 16 + fq] = o;
    }
}

__global__ __launch_bounds__(256) void agg_gcn_pool(const float* __restrict__ H,
                                                    const int* __restrict__ offs,
                                                    const int* __restrict__ csr_src,
                                                    const float* __restrict__ csr_norm,
                                                    const float* __restrict__ dinv,
                                                    const float* __restrict__ bias,
                                                    const float* __restrict__ fcw,
                                                    float* __restrict__ p) {
    int wid = (blockIdx.x * 256 + threadIdx.x) >> 6;
    int lane = threadIdx.x & 63;
    if (wid >= N_NODES) return;
    float4 r;
    agg_body((const float4*)H, wid, lane, offs, csr_src, csr_norm, dinv, r);
    int fq = lane & 15;
    float4 b4 = ((const float4*)bias)[fq];
    float4 f4 = ((const float4*)fcw)[fq];
    float v = fmaxf(r.x + b4.x, 0.f) * f4.x + fmaxf(r.y + b4.y, 0.f) * f4.y
            + fmaxf(r.z + b4.z, 0.f) * f4.z + fmaxf(r.w + b4.w, 0.f) * f4.w;
    // sum across the 16 feature-quads (all 4 subgroups already identical)
    v += __shfl_xor(v, 1); v += __shfl_xor(v, 2);
    v += __shfl_xor(v, 4); v += __shfl_xor(v, 8);
    if (lane == 0) p[wid] = v;
}

// ---------------- per-graph segmented mean via binary search (no atomics) ----

__device__ inline int lower_bound_batch(const int* __restrict__ batch, int key) {
    int lo = 0, hi = N_NODES;
    while (lo < hi) {
        int mid = (lo + hi) >> 1;
        if (batch[mid] < key) lo = mid + 1; else hi = mid;
    }
    return lo;
}

__global__ __launch_bounds__(256) void graph_reduce(const float* __restrict__ p,
                                                    const int* __restrict__ batch,
                                                    const float* __restrict__ fcb,
                                                    float* __restrict__ out) {
    __shared__ float red[4];
    int g = blockIdx.x;
    int s0 = lower_bound_batch(batch, g);
    int s1 = lower_bound_batch(batch, g + 1);
    float acc = 0.f;
    for (int i = s0 + threadIdx.x; i < s1; i += 256) acc += p[i];
    #pragma unroll
    for (int o = 32; o > 0; o >>= 1) acc += __shfl_xor(acc, o);
    int lane = threadIdx.x & 63, wv = threadIdx.x >> 6;
    if (lane == 0) red[wv] = acc;
    __syncthreads();
    if (threadIdx.x == 0) {
        float sum = red[0] + red[1] + red[2] + red[3];
        out[g] = sum / fmaxf((float)(s1 - s0), 1.f) + fcb[0];
    }
}

// ---------------- launch ----------------

extern "C" void kernel_launch(void* const* d_in, const int* in_sizes, int n_in,
                              void* d_out, int out_size, void* d_ws, size_t ws_size,
                              hipStream_t stream) {
    const float* x    = (const float*)d_in[0];
    const int*   ei   = (const int*)d_in[1];
    const int*   batch= (const int*)d_in[2];
    const float* w0   = (const float*)d_in[3];
    const float* b0   = (const float*)d_in[4];
    const float* w1   = (const float*)d_in[5];
    const float* b1   = (const float*)d_in[6];
    const float* w2   = (const float*)d_in[7];
    const float* b2   = (const float*)d_in[8];
    const float* fcw  = (const float*)d_in[9];
    const float* fcb  = (const float*)d_in[10];
    float* out = (float*)d_out;

    const int* src_e = ei;              // edge_index[0]
    const int* dst_e = ei + N_EDGES;    // edge_index[1]

    char* w = (char*)d_ws;
    size_t o = 0;
    int*   deg_cnt  = (int*)(w + o);   o += (size_t)N_NODES * 4;
    float* dinv     = (float*)(w + o); o += (size_t)N_NODES * 4;
    int*   offs     = (int*)(w + o);   o += (size_t)(N_NODES + 8) * 4;  // N_NODES+1 used
    int*   cursor   = (int*)(w + o);   o += (size_t)N_NODES * 4;
    int*   bsum     = (int*)(w + o);   o += 512 * 4;
    int*   csr_src  = (int*)(w + o);   o += (size_t)N_EDGES * 4;
    float* csr_norm = (float*)(w + o); o += (size_t)N_EDGES * 4;
    float* bufA     = (float*)(w + o); o += (size_t)N_NODES * 64 * 4;
    float* bufB     = (float*)(w + o); o += (size_t)N_NODES * 64 * 4;
    float* pvec     = (float*)(w + o); o += (size_t)N_NODES * 4;

    hipMemsetAsync(deg_cnt, 0, (size_t)N_NODES * 4, stream);
    hipMemsetAsync(cursor,  0, (size_t)N_NODES * 4, stream);

    count_deg<<<(N_EDGES + 255) / 256, 256, 0, stream>>>(dst_e, deg_cnt);
    compute_dinv<<<(N_NODES + 255) / 256, 256, 0, stream>>>(deg_cnt, dinv);
    scan1<<<SCAN_BLOCKS, 256, 0, stream>>>(deg_cnt, offs, bsum);
    scan2<<<1, 512, 0, stream>>>(bsum, SCAN_BLOCKS);
    scan3<<<SCAN_BLOCKS, 256, 0, stream>>>(offs, bsum);
    fill_csr<<<(N_EDGES + 255) / 256, 256, 0, stream>>>(src_e, dst_e, offs, cursor, dinv,
                                                        csr_src, csr_norm);

    const int GEMM_BLOCKS = (N_NODES + 63) / 64;   // 1563
    const int AGG_BLOCKS  = (N_NODES + 3) / 4;     // 25000

    gemm64<<<GEMM_BLOCKS, 256, 0, stream>>>(x, w0, bufA);
    agg_gcn<<<AGG_BLOCKS, 256, 0, stream>>>(bufA, offs, csr_src, csr_norm, dinv, b0, bufB);

    gemm64<<<GEMM_BLOCKS, 256, 0, stream>>>(bufB, w1, bufA);
    agg_gcn<<<AGG_BLOCKS, 256, 0, stream>>>(bufA, offs, csr_src, csr_norm, dinv, b1, bufB);

    gemm64<<<GEMM_BLOCKS, 256, 0, stream>>>(bufB, w2, bufA);
    agg_gcn_pool<<<AGG_BLOCKS, 256, 0, stream>>>(bufA, offs, csr_src, csr_norm, dinv, b2,
                                                 fcw, pvec);

    graph_reduce<<<N_GRAPHS, 256, 0, stream>>>(pvec, batch, fcb, out);
}

// Round 5
// 479.695 us; speedup vs baseline: 1.8278x; 1.1626x over previous
//
#include <hip/hip_runtime.h>
#include <hip/hip_fp16.h>

#define N_NODES 100000
#define N_EDGES 1280000
#define N_GRAPHS 512
#define SCAN_BLOCKS 391   // ceil(100000/256)

// ---------------- degree count ----------------

__global__ void count_deg(const int* __restrict__ dst, int* __restrict__ cnt) {
    int e = blockIdx.x * blockDim.x + threadIdx.x;
    if (e < N_EDGES) atomicAdd(&cnt[dst[e]], 1);
}

// ---------------- exclusive prefix scan (3-kernel), scan1 also emits dinv ----

__global__ void scan1(const int* __restrict__ cnt, int* __restrict__ offs,
                      int* __restrict__ bsum, float* __restrict__ dinv) {
    __shared__ int s[256];
    int t = threadIdx.x;
    int i = blockIdx.x * 256 + t;
    int v = (i < N_NODES) ? cnt[i] : 0;
    if (i < N_NODES) dinv[i] = 1.0f / sqrtf((float)v + 1.0f);
    s[t] = v; __syncthreads();
    for (int d = 1; d < 256; d <<= 1) {
        int x = (t >= d) ? s[t - d] : 0;
        __syncthreads();
        s[t] += x;
        __syncthreads();
    }
    if (i < N_NODES) offs[i] = s[t] - v;
    if (t == 255) bsum[blockIdx.x] = s[t];
}

__global__ void scan2(int* __restrict__ bsum, int nb) {
    __shared__ int s[512];
    int t = threadIdx.x;
    int v = (t < nb) ? bsum[t] : 0;
    s[t] = v; __syncthreads();
    for (int d = 1; d < 512; d <<= 1) {
        int x = (t >= d) ? s[t - d] : 0;
        __syncthreads();
        s[t] += x;
        __syncthreads();
    }
    if (t < nb) bsum[t] = s[t] - v;
}

__global__ void scan3(int* __restrict__ offs, const int* __restrict__ bsum) {
    int i = blockIdx.x * 256 + threadIdx.x;
    if (i < N_NODES) offs[i] += bsum[blockIdx.x];
    if (i == 0) offs[N_NODES] = N_EDGES;
}

// ---------------- CSR fill: single int2 record per edge (src, norm bits) ----

__global__ void fill_csr(const int* __restrict__ src, const int* __restrict__ dst,
                         const int* __restrict__ offs, int* __restrict__ cursor,
                         const float* __restrict__ dinv, int2* __restrict__ rec) {
    int e = blockIdx.x * blockDim.x + threadIdx.x;
    if (e < N_EDGES) {
        int d = dst[e], s = src[e];
        int p = offs[d] + atomicAdd(&cursor[d], 1);
        rec[p] = make_int2(s, __float_as_int(dinv[s] * dinv[d]));
    }
}

// ---------------- fp32 GEMM [N x 64] @ [64 x 64], fp16 output ----------------
// R1-proven structure: acc[4][4] (16 VGPRs), no spills. DO NOT grow the
// accumulator tile: R2's acc[8][4] variant hit VGPR=256 -> scratch spills.

__global__ __launch_bounds__(256) void gemm64(const float* __restrict__ X,
                                              const float* __restrict__ W,
                                              __half* __restrict__ H) {
    __shared__ float Xt[64][68];   // transposed tile: Xt[k][node]
    __shared__ float Ws[64][64];   // Ws[k][j]
    int t = threadIdx.x;
    int base = blockIdx.x * 64;

    {
        const float4* Wv = (const float4*)W;
        float4* Wsv = (float4*)Ws;
        Wsv[t]        = Wv[t];
        Wsv[t + 256]  = Wv[t + 256];
        Wsv[t + 512]  = Wv[t + 512];
        Wsv[t + 768]  = Wv[t + 768];
    }
    {
        int r = t >> 2;
        int k0 = (t & 3) * 16;
        int row = base + r;
        if (row < N_NODES) {
            const float4* xr = (const float4*)(X + (size_t)row * 64 + k0);
            #pragma unroll
            for (int q = 0; q < 4; q++) {
                float4 v = xr[q];
                int k = k0 + q * 4;
                Xt[k + 0][r] = v.x; Xt[k + 1][r] = v.y;
                Xt[k + 2][r] = v.z; Xt[k + 3][r] = v.w;
            }
        } else {
            #pragma unroll
            for (int q = 0; q < 4; q++) {
                int k = k0 + q * 4;
                Xt[k][r] = 0.f; Xt[k + 1][r] = 0.f; Xt[k + 2][r] = 0.f; Xt[k + 3][r] = 0.f;
            }
        }
    }
    __syncthreads();

    int tx = t & 15, ty = t >> 4;
    int j0 = tx * 4, n0 = ty * 4;
    float acc[4][4] = {};
    #pragma unroll
    for (int k = 0; k < 64; k++) {
        float4 a = *(const float4*)&Xt[k][n0];
        float4 w = *(const float4*)&Ws[k][j0];
        acc[0][0] += a.x * w.x; acc[0][1] += a.x * w.y; acc[0][2] += a.x * w.z; acc[0][3] += a.x * w.w;
        acc[1][0] += a.y * w.x; acc[1][1] += a.y * w.y; acc[1][2] += a.y * w.z; acc[1][3] += a.y * w.w;
        acc[2][0] += a.z * w.x; acc[2][1] += a.z * w.y; acc[2][2] += a.z * w.z; acc[2][3] += a.z * w.w;
        acc[3][0] += a.w * w.x; acc[3][1] += a.w * w.y; acc[3][2] += a.w * w.z; acc[3][3] += a.w * w.w;
    }
    #pragma unroll
    for (int i = 0; i < 4; i++) {
        int row = base + n0 + i;
        if (row < N_NODES) {
            __half2 h01 = __float22half2_rn(make_float2(acc[i][0], acc[i][1]));
            __half2 h23 = __float22half2_rn(make_float2(acc[i][2], acc[i][3]));
            uint2 u;
            u.x = *(unsigned int*)&h01;
            u.y = *(unsigned int*)&h23;
            *(uint2*)((char*)H + (size_t)row * 128 + j0 * 2) = u;
        }
    }
}

// ------------- aggregation: wave per node, 4 edge-subgroups x 16 feature-quads -------------
// H is fp16 (row = 128B = 16 uint2 chunks); edge record = int2(src, norm).

__device__ inline void agg_body(const uint2* __restrict__ Hh, int wid, int lane,
                                const int* __restrict__ offs,
                                const int2* __restrict__ rec,
                                const float* __restrict__ dinv,
                                float4& out) {
    int eg = lane >> 4;       // 0..3
    int fq = lane & 15;       // feature quad
    int beg = offs[wid], end = offs[wid + 1];
    float di = dinv[wid];
    uint2 us = Hh[(size_t)wid * 16 + fq];

    float4 a0 = {0.f, 0.f, 0.f, 0.f};
    float4 a1 = {0.f, 0.f, 0.f, 0.f};
    int e = beg + eg;
    for (; e + 4 < end; e += 8) {
        int2 r0 = rec[e];
        int2 r1 = rec[e + 4];
        uint2 u0 = Hh[(size_t)r0.x * 16 + fq];
        uint2 u1 = Hh[(size_t)r1.x * 16 + fq];
        float n0 = __int_as_float(r0.y), n1 = __int_as_float(r1.y);
        float2 f00 = __half22float2(*(__half2*)&u0.x);
        float2 f01 = __half22float2(*(__half2*)&u0.y);
        float2 f10 = __half22float2(*(__half2*)&u1.x);
        float2 f11 = __half22float2(*(__half2*)&u1.y);
        a0.x += f00.x * n0; a0.y += f00.y * n0; a0.z += f01.x * n0; a0.w += f01.y * n0;
        a1.x += f10.x * n1; a1.y += f10.y * n1; a1.z += f11.x * n1; a1.w += f11.y * n1;
    }
    if (e < end) {
        int2 r0 = rec[e];
        uint2 u0 = Hh[(size_t)r0.x * 16 + fq];
        float n0 = __int_as_float(r0.y);
        float2 f00 = __half22float2(*(__half2*)&u0.x);
        float2 f01 = __half22float2(*(__half2*)&u0.y);
        a0.x += f00.x * n0; a0.y += f00.y * n0; a0.z += f01.x * n0; a0.w += f01.y * n0;
    }
    a0.x += a1.x; a0.y += a1.y; a0.z += a1.z; a0.w += a1.w;
    // reduce across the 4 edge-subgroups
    a0.x += __shfl_xor(a0.x, 16); a0.y += __shfl_xor(a0.y, 16);
    a0.z += __shfl_xor(a0.z, 16); a0.w += __shfl_xor(a0.w, 16);
    a0.x += __shfl_xor(a0.x, 32); a0.y += __shfl_xor(a0.y, 32);
    a0.z += __shfl_xor(a0.z, 32); a0.w += __shfl_xor(a0.w, 32);
    float2 s01 = __half22float2(*(__half2*)&us.x);
    float2 s23 = __half22float2(*(__half2*)&us.y);
    float dd = di * di;
    out.x = a0.x + s01.x * dd; out.y = a0.y + s01.y * dd;
    out.z = a0.z + s23.x * dd; out.w = a0.w + s23.y * dd;
}

__global__ __launch_bounds__(256) void agg_gcn(const __half* __restrict__ H,
                                               const int* __restrict__ offs,
                                               const int2* __restrict__ rec,
                                               const float* __restrict__ dinv,
                                               const float* __restrict__ bias,
                                               float* __restrict__ Out) {
    int wid = (blockIdx.x * 256 + threadIdx.x) >> 6;
    int lane = threadIdx.x & 63;
    if (wid >= N_NODES) return;
    float4 r;
    agg_body((const uint2*)H, wid, lane, offs, rec, dinv, r);
    int fq = lane & 15;
    if ((lane >> 4) == 0) {
        float4 b4 = ((const float4*)bias)[fq];
        float4 o;
        o.x = fmaxf(r.x + b4.x, 0.f); o.y = fmaxf(r.y + b4.y, 0.f);
        o.z = fmaxf(r.z + b4.z, 0.f); o.w = fmaxf(r.w + b4.w, 0.f);
        ((float4*)Out)[(size_t)wid * 16 + fq] = o;
    }
}

__global__ __launch_bounds__(256) void agg_gcn_pool(const __half* __restrict__ H,
                                                    const int* __restrict__ offs,
                                                    const int2* __restrict__ rec,
                                                    const float* __restrict__ dinv,
                                                    const float* __restrict__ bias,
                                                    const float* __restrict__ fcw,
                                                    float* __restrict__ p) {
    int wid = (blockIdx.x * 256 + threadIdx.x) >> 6;
    int lane = threadIdx.x & 63;
    if (wid >= N_NODES) return;
    float4 r;
    agg_body((const uint2*)H, wid, lane, offs, rec, dinv, r);
    int fq = lane & 15;
    float4 b4 = ((const float4*)bias)[fq];
    float4 f4 = ((const float4*)fcw)[fq];
    float v = fmaxf(r.x + b4.x, 0.f) * f4.x + fmaxf(r.y + b4.y, 0.f) * f4.y
            + fmaxf(r.z + b4.z, 0.f) * f4.z + fmaxf(r.w + b4.w, 0.f) * f4.w;
    v += __shfl_xor(v, 1); v += __shfl_xor(v, 2);
    v += __shfl_xor(v, 4); v += __shfl_xor(v, 8);
    if (lane == 0) p[wid] = v;
}

// ---------------- per-graph segmented mean via binary search (no atomics) ----

__device__ inline int lower_bound_batch(const int* __restrict__ batch, int key) {
    int lo = 0, hi = N_NODES;
    while (lo < hi) {
        int mid = (lo + hi) >> 1;
        if (batch[mid] < key) lo = mid + 1; else hi = mid;
    }
    return lo;
}

__global__ __launch_bounds__(256) void graph_reduce(const float* __restrict__ p,
                                                    const int* __restrict__ batch,
                                                    const float* __restrict__ fcb,
                                                    float* __restrict__ out) {
    __shared__ float red[4];
    int g = blockIdx.x;
    int s0 = lower_bound_batch(batch, g);
    int s1 = lower_bound_batch(batch, g + 1);
    float acc = 0.f;
    for (int i = s0 + threadIdx.x; i < s1; i += 256) acc += p[i];
    #pragma unroll
    for (int o = 32; o > 0; o >>= 1) acc += __shfl_xor(acc, o);
    int lane = threadIdx.x & 63, wv = threadIdx.x >> 6;
    if (lane == 0) red[wv] = acc;
    __syncthreads();
    if (threadIdx.x == 0) {
        float sum = red[0] + red[1] + red[2] + red[3];
        out[g] = sum / fmaxf((float)(s1 - s0), 1.f) + fcb[0];
    }
}

// ---------------- launch ----------------

extern "C" void kernel_launch(void* const* d_in, const int* in_sizes, int n_in,
                              void* d_out, int out_size, void* d_ws, size_t ws_size,
                              hipStream_t stream) {
    const float* x    = (const float*)d_in[0];
    const int*   ei   = (const int*)d_in[1];
    const int*   batch= (const int*)d_in[2];
    const float* w0   = (const float*)d_in[3];
    const float* b0   = (const float*)d_in[4];
    const float* w1   = (const float*)d_in[5];
    const float* b1   = (const float*)d_in[6];
    const float* w2   = (const float*)d_in[7];
    const float* b2   = (const float*)d_in[8];
    const float* fcw  = (const float*)d_in[9];
    const float* fcb  = (const float*)d_in[10];
    float* out = (float*)d_out;

    const int* src_e = ei;              // edge_index[0]
    const int* dst_e = ei + N_EDGES;    // edge_index[1]

    char* w = (char*)d_ws;
    size_t o = 0;
    int*    deg_cnt = (int*)(w + o);    o += (size_t)N_NODES * 4;
    float*  dinv    = (float*)(w + o);  o += (size_t)N_NODES * 4;
    int*    offs    = (int*)(w + o);    o += (size_t)(N_NODES + 8) * 4;  // N_NODES+1 used
    int*    cursor  = (int*)(w + o);    o += (size_t)N_NODES * 4;
    int*    bsum    = (int*)(w + o);    o += 512 * 4;
    int2*   rec     = (int2*)(w + o);   o += (size_t)N_EDGES * 8;        // 10.24MB
    __half* bufA    = (__half*)(w + o); o += (size_t)N_NODES * 64 * 2;   // 12.8MB fp16
    float*  bufB    = (float*)(w + o);  o += (size_t)N_NODES * 64 * 4;   // 25.6MB fp32
    float*  pvec    = (float*)(w + o);  o += (size_t)N_NODES * 4;

    hipMemsetAsync(deg_cnt, 0, (size_t)N_NODES * 4, stream);
    hipMemsetAsync(cursor,  0, (size_t)N_NODES * 4, stream);

    count_deg<<<(N_EDGES + 255) / 256, 256, 0, stream>>>(dst_e, deg_cnt);
    scan1<<<SCAN_BLOCKS, 256, 0, stream>>>(deg_cnt, offs, bsum, dinv);
    scan2<<<1, 512, 0, stream>>>(bsum, SCAN_BLOCKS);
    scan3<<<SCAN_BLOCKS, 256, 0, stream>>>(offs, bsum);
    fill_csr<<<(N_EDGES + 255) / 256, 256, 0, stream>>>(src_e, dst_e, offs, cursor, dinv, rec);

    const int GEMM_BLOCKS = (N_NODES + 63) / 64;   // 1563
    const int AGG_BLOCKS  = (N_NODES + 3) / 4;     // 25000

    gemm64<<<GEMM_BLOCKS, 256, 0, stream>>>(x, w0, bufA);
    agg_gcn<<<AGG_BLOCKS, 256, 0, stream>>>(bufA, offs, rec, dinv, b0, bufB);

    gemm64<<<GEMM_BLOCKS, 256, 0, stream>>>(bufB, w1, bufA);
    agg_gcn<<<AGG_BLOCKS, 256, 0, stream>>>(bufA, offs, rec, dinv, b1, bufB);

    gemm64<<<GEMM_BLOCKS, 256, 0, stream>>>(bufB, w2, bufA);
    agg_gcn_pool<<<AGG_BLOCKS, 256, 0, stream>>>(bufA, offs, rec, dinv, b2, fcw, pvec);

    graph_reduce<<<N_GRAPHS, 256, 0, stream>>>(pvec, batch, fcb, out);
}